// Round 17
// baseline (710.792 us; speedup 1.0000x reference)
//
#include <hip/hip_runtime.h>
#include <hip/hip_bf16.h>

typedef __bf16 bf16x8 __attribute__((ext_vector_type(8)));
typedef float f32x4 __attribute__((ext_vector_type(4)));
typedef unsigned short u16;
typedef u16 u16x8 __attribute__((ext_vector_type(8)));
typedef u16 u16x4 __attribute__((ext_vector_type(4)));

#define B_ 4
#define S_ 1024
#define D_ 1024
#define E_ 4
#define H_ 16
#define FF_ 4096
#define N_ 4096

__device__ __forceinline__ u16 f2bf(float f) {
  __hip_bfloat16 h = __float2bfloat16(f);
  return *reinterpret_cast<u16*>(&h);
}
__device__ __forceinline__ float bf2f(u16 v) {
  return __uint_as_float(((unsigned)v) << 16);
}

#define BAR()                         \
  {                                   \
    asm volatile("" ::: "memory");    \
    __builtin_amdgcn_s_barrier();     \
    asm volatile("" ::: "memory");    \
  }

// ------- transpose + f32->bf16 convert (z-batched): dst[z][c][r] = src[z][r][c] -------
__global__ __launch_bounds__(256) void tcvt(const float* __restrict__ src,
                                            u16* __restrict__ dst, int R, int C) {
  __shared__ float t[32][33];
  long base = (long)blockIdx.z * R * C;
  src += base; dst += base;
  int r0 = blockIdx.y * 32, c0 = blockIdx.x * 32;
  int tx = threadIdx.x, ty = threadIdx.y;  // 32 x 8
#pragma unroll
  for (int i = 0; i < 4; i++)
    t[ty + i * 8][tx] = src[(long)(r0 + ty + i * 8) * C + c0 + tx];
  __syncthreads();
#pragma unroll
  for (int i = 0; i < 4; i++)
    dst[(long)(c0 + ty + i * 8) * R + r0 + tx] = f2bf(t[tx][ty + i * 8]);
}

// ---------------- LN + router softmax (+ optional expert expand), vectorized x4 ------
// YMODE=1: row = X[n] + sum_e s_a[e]*bpr[e] + sum_e s_a[e]*prt[e] (prt TILE-major,
// 4 col-tiles); writes ybuf. EXPAND=1: Aout = (scale? score[e]:1)*(hn*g[e]+b[e]).
template <int YMODE, int EXPAND>
__global__ __launch_bounds__(256) void ln_router_expand(
    const float* __restrict__ X, const float* __restrict__ Wr, const float* __restrict__ br,
    const float* __restrict__ g, const float* __restrict__ bb,
    float* __restrict__ score_out, u16* __restrict__ Aout,
    long stride_e, long stride_n, int scale_flag,
    const float* __restrict__ score_a, const float* __restrict__ bpr,
    const u16* __restrict__ prt, float* __restrict__ ybuf) {
  int n = blockIdx.x, t = threadIdx.x;
  int lane = t & 63, wave = t >> 6;
  int d0 = t * 4;
  const float* xr = X + (long)n * D_;
  float4 xv = *reinterpret_cast<const float4*>(&xr[d0]);
  if (YMODE) {
    float4 sa4 = reinterpret_cast<const float4*>(score_a)[n];
    float sw[4] = {sa4.x, sa4.y, sa4.z, sa4.w};
    float4 b0 = *reinterpret_cast<const float4*>(&bpr[d0]);
    float4 b1 = *reinterpret_cast<const float4*>(&bpr[D_ + d0]);
    float4 b2 = *reinterpret_cast<const float4*>(&bpr[2 * D_ + d0]);
    float4 b3 = *reinterpret_cast<const float4*>(&bpr[3 * D_ + d0]);
    xv.x += sa4.x * b0.x + sa4.y * b1.x + sa4.z * b2.x + sa4.w * b3.x;
    xv.y += sa4.x * b0.y + sa4.y * b1.y + sa4.z * b2.y + sa4.w * b3.y;
    xv.z += sa4.x * b0.z + sa4.y * b1.z + sa4.z * b2.z + sa4.w * b3.z;
    xv.w += sa4.x * b0.w + sa4.y * b1.w + sa4.z * b2.w + sa4.w * b3.w;
#pragma unroll
    for (int zz = 0; zz < 4; zz++) {
      long toff = ((((long)zz * 16 + (n >> 8)) * 4 + (d0 >> 8)) << 16) +
                  (long)(n & 255) * 256 + (d0 & 255);
      u16x4 pv = *reinterpret_cast<const u16x4*>(&prt[toff]);
      xv.x += sw[zz] * bf2f(pv[0]); xv.y += sw[zz] * bf2f(pv[1]);
      xv.z += sw[zz] * bf2f(pv[2]); xv.w += sw[zz] * bf2f(pv[3]);
    }
    *reinterpret_cast<float4*>(&ybuf[(long)n * D_ + d0]) = xv;
  }
  float vals[6];
  vals[0] = xv.x + xv.y + xv.z + xv.w;
  vals[1] = xv.x * xv.x + xv.y * xv.y + xv.z * xv.z + xv.w * xv.w;
  {
    float4 w0 = reinterpret_cast<const float4*>(Wr)[d0];
    float4 w1 = reinterpret_cast<const float4*>(Wr)[d0 + 1];
    float4 w2 = reinterpret_cast<const float4*>(Wr)[d0 + 2];
    float4 w3 = reinterpret_cast<const float4*>(Wr)[d0 + 3];
    vals[2] = xv.x * w0.x + xv.y * w1.x + xv.z * w2.x + xv.w * w3.x;
    vals[3] = xv.x * w0.y + xv.y * w1.y + xv.z * w2.y + xv.w * w3.y;
    vals[4] = xv.x * w0.z + xv.y * w1.z + xv.z * w2.z + xv.w * w3.z;
    vals[5] = xv.x * w0.w + xv.y * w1.w + xv.z * w2.w + xv.w * w3.w;
  }
#pragma unroll
  for (int o = 1; o < 64; o <<= 1) {
#pragma unroll
    for (int j = 0; j < 6; j++) vals[j] += __shfl_xor(vals[j], o, 64);
  }
  __shared__ float red[4][6];
  if (lane == 0) {
#pragma unroll
    for (int j = 0; j < 6; j++) red[wave][j] = vals[j];
  }
  __syncthreads();
  float tot[6];
#pragma unroll
  for (int j = 0; j < 6; j++) tot[j] = red[0][j] + red[1][j] + red[2][j] + red[3][j];
  float mean = tot[0] * (1.0f / D_);
  float var = tot[1] * (1.0f / D_) - mean * mean;
  float rstd = rsqrtf(var + 1e-5f);
  float lg0 = tot[2] + br[0], lg1 = tot[3] + br[1], lg2 = tot[4] + br[2], lg3 = tot[5] + br[3];
  float mx = fmaxf(fmaxf(lg0, lg1), fmaxf(lg2, lg3));
  float e0 = __expf(lg0 - mx), e1 = __expf(lg1 - mx), e2 = __expf(lg2 - mx), e3 = __expf(lg3 - mx);
  float inv = 1.0f / (e0 + e1 + e2 + e3);
  float sc[4] = {e0 * inv, e1 * inv, e2 * inv, e3 * inv};
  if (t == 0) {
    float4 s4 = make_float4(sc[0], sc[1], sc[2], sc[3]);
    *reinterpret_cast<float4*>(&score_out[(long)n * 4]) = s4;
  }
  float4 hn;
  hn.x = (xv.x - mean) * rstd; hn.y = (xv.y - mean) * rstd;
  hn.z = (xv.z - mean) * rstd; hn.w = (xv.w - mean) * rstd;
  if (EXPAND) {
#pragma unroll
    for (int e = 0; e < 4; e++) {
      float4 ge = *reinterpret_cast<const float4*>(&g[e * D_ + d0]);
      float4 be = *reinterpret_cast<const float4*>(&bb[e * D_ + d0]);
      float s = scale_flag ? sc[e] : 1.0f;
      u16x4 o;
      o[0] = f2bf((hn.x * ge.x + be.x) * s);
      o[1] = f2bf((hn.y * ge.y + be.y) * s);
      o[2] = f2bf((hn.z * ge.z + be.z) * s);
      o[3] = f2bf((hn.w * ge.w + be.w) * s);
      *reinterpret_cast<u16x4*>(&Aout[(long)e * stride_e + (long)n * stride_n + d0]) = o;
    }
  } else {
    u16x4 o;
    o[0] = f2bf(hn.x); o[1] = f2bf(hn.y); o[2] = f2bf(hn.z); o[3] = f2bf(hn.w);
    *reinterpret_cast<u16x4*>(&Aout[(long)n * 1024 + d0]) = o;
  }
}

// ---- mixq: qkvb[n,f] = sum_e qp_tiled[e][n,f] + sum_e s[n,e]*bqkv[e,f] --------------
// qp is tile-major: [e][16 row-tiles][12 col-tiles][256][256]
__global__ __launch_bounds__(256) void mixq(const u16* __restrict__ qp,
                                            const float* __restrict__ score_a,
                                            const float* __restrict__ bqkv,
                                            u16* __restrict__ qkvb) {
  int c = blockIdx.x * 256 + threadIdx.x;   // 8-col chunk id; 384 chunks/row
  int n = c / 384, f0 = (c % 384) * 8;
  float4 s4 = reinterpret_cast<const float4*>(score_a)[n];
  float sw[4] = {s4.x, s4.y, s4.z, s4.w};
  float acc[8] = {};
#pragma unroll
  for (int e = 0; e < 4; e++) {
    long toff = ((((long)e * 16 + (n >> 8)) * 12 + (f0 >> 8)) << 16) +
                (long)(n & 255) * 256 + (f0 & 255);
    u16x8 pv = *reinterpret_cast<const u16x8*>(&qp[toff]);
#pragma unroll
    for (int j = 0; j < 8; j++) acc[j] += bf2f(pv[j]) + sw[e] * bqkv[e * 3072 + f0 + j];
  }
  u16x8 o;
#pragma unroll
  for (int j = 0; j < 8; j++) o[j] = f2bf(acc[j]);
  *reinterpret_cast<u16x8*>(&qkvb[(long)n * 3072 + f0]) = o;
}

// ======== 8-wave 256x256 GEMM, reg-double-buffered frags, 2 phases/K-tile ============
// Round-8 K-loop (frozen). C write is TILE-MAJOR: block (z,by,bx) owns one contiguous
// 128KB tile at ((z*gy+by)*gx+bx)<<16 — kills the 2.2x HBM write amplification of the
// row-major scatter. AT=1: A operand is tile-major (p2 reading fc's inter).
// MODE 2: gelu-fc (per-z bias bias+z*N, score col z). MODE 4: plain partials.
template <int MODE, int AT>
__global__ __launch_bounds__(512, 2) void g8(
    const u16* __restrict__ A, const u16* __restrict__ Bt, int K, int N, int kslice,
    const float* __restrict__ score, const float* __restrict__ bias,
    u16* __restrict__ outb, long az, long bz) {
  __shared__ __align__(16) u16 lds0[65536];  // 128 KiB
  const int tid = threadIdx.x;
  const int w = tid >> 6, lane = tid & 63;
  const int l15 = lane & 15, l4 = lane >> 4;
  const int wr = w >> 2, wc = w & 3;

  // ---- XCD-aware bijective swizzle ----
  const int gx = gridDim.x, gy = gridDim.y;
  const int total = gx * gy * gridDim.z;
  const int flat = blockIdx.x + gx * (blockIdx.y + gy * blockIdx.z);
  const int cpx = total >> 3;
  const int nf = (flat & 7) * cpx + (flat >> 3);
  const int bxi = nf % gx;
  const int tmp = nf / gx;
  const int byi = tmp % gy;
  const int z = tmp / gy;

  const long bm = (long)byi * 256, bn = (long)bxi * 256;
  const long k0 = bz ? 0L : (long)z * kslice;
  const u16* Az = bz ? (A + (long)z * az) : A;
  const u16* Btz = bz ? (Bt + (long)z * bz) : Bt;
  const int nt = kslice >> 6;

  // staging geometry
  const int cp = lane & 3;
  const int sr0 = w * 32 + (lane >> 2);
  const int sr1 = sr0 + 16;
  const int cl0 = cp ^ ((sr0 >> 1) & 3);
  const int cl1 = cp ^ ((sr1 >> 1) & 3);
  const u16 *gA0, *gA1;
  if (AT) {
    // tile-major A: row-tile byi, k-tiles of 256; in-tile row stride 256 u16
    const u16* At = Az + (((long)byi * (kslice >> 8)) << 16);
    gA0 = At + sr0 * 256 + cl0 * 8;
    gA1 = At + sr1 * 256 + cl1 * 8;
  } else {
    gA0 = Az + (bm + sr0) * (long)K + k0 + cl0 * 8;
    gA1 = Az + (bm + sr1) * (long)K + k0 + cl1 * 8;
  }
  const u16* gB0 = Btz + (bn + sr0) * (long)K + k0 + cl0 * 8;
  const u16* gB1 = Btz + (bn + sr1) * (long)K + k0 + cl1 * 8;
  const int e0 = w * 1024;
  const int e1 = w * 1024 + 512;

  // frag-read bases (u16 units within a region)
  const int chA = l4 ^ ((l15 >> 1) & 3);
  const int rdA = (wr * 128 + l15) * 32 + chA * 8;  // + mi*512
  const int rdB = (wc * 64 + l15) * 32 + chA * 8;   // + ni*512

#define KMAP(ko) (AT ? ((((long)(ko) >> 8) << 16) | ((long)(ko) & 255)) : (long)(ko))
#define GLD(gsrc, ldsoff)                                                              \
  __builtin_amdgcn_global_load_lds(                                                    \
      (const __attribute__((address_space(1))) void*)(gsrc),                           \
      (__attribute__((address_space(3))) void*)(lds0 + (ldsoff)), 16, 0, 0)

  // -------- prologue: stage tiles 0 and 1 fully --------
  GLD(gA0, 0 + e0);
  GLD(gA1, 0 + e1);
  GLD(gB0, 16384 + e0);
  GLD(gB1, 16384 + e1);
  GLD(gA0 + KMAP(32), 8192 + e0);
  GLD(gA1 + KMAP(32), 8192 + e1);
  GLD(gB0 + 32, 24576 + e0);
  GLD(gB1 + 32, 24576 + e1);
  if (nt > 1) {
    GLD(gA0 + KMAP(64), 32768 + e0);
    GLD(gA1 + KMAP(64), 32768 + e1);
    GLD(gB0 + 64, 32768 + 16384 + e0);
    GLD(gB1 + 64, 32768 + 16384 + e1);
    GLD(gA0 + KMAP(96), 32768 + 8192 + e0);
    GLD(gA1 + KMAP(96), 32768 + 8192 + e1);
    GLD(gB0 + 96, 32768 + 24576 + e0);
    GLD(gB1 + 96, 32768 + 24576 + e1);
    asm volatile("s_waitcnt vmcnt(8)" ::: "memory");
  } else {
    asm volatile("s_waitcnt vmcnt(0)" ::: "memory");
  }
  BAR();

  f32x4 acc[8][4] = {};
  bf16x8 aC[8], bC[4], aN[8], bN[4];

  // initial frag load: kc0 of tile 0
#pragma unroll
  for (int i = 0; i < 8; i++) aC[i] = *(const bf16x8*)(lds0 + rdA + i * 512);
#pragma unroll
  for (int i = 0; i < 4; i++) bC[i] = *(const bf16x8*)(lds0 + 16384 + rdB + i * 512);

  for (int t = 0; t < nt; ++t) {
    const int base = (t & 1) * 32768;
    const int nb = base ^ 32768;
    const long ko2 = (long)(t + 2) * 64;
    // ---------- phase A: read kc1(t)->N, stage kc0(t+2), MFMA on C ----------
#pragma unroll
    for (int i = 0; i < 8; i++) aN[i] = *(const bf16x8*)(lds0 + base + 8192 + rdA + i * 512);
#pragma unroll
    for (int i = 0; i < 4; i++) bN[i] = *(const bf16x8*)(lds0 + base + 24576 + rdB + i * 512);
    if (t + 2 < nt) {
      GLD(gA0 + KMAP(ko2), base + e0);
      GLD(gA1 + KMAP(ko2), base + e1);
      GLD(gB0 + ko2, base + 16384 + e0);
      GLD(gB1 + ko2, base + 16384 + e1);
    }
    __builtin_amdgcn_s_setprio(1);
#pragma unroll
    for (int mi = 0; mi < 8; mi++)
#pragma unroll
      for (int ni = 0; ni < 4; ni++)
        acc[mi][ni] = __builtin_amdgcn_mfma_f32_16x16x32_bf16(aC[mi], bC[ni], acc[mi][ni], 0, 0, 0);
    __builtin_amdgcn_s_setprio(0);
    asm volatile("s_waitcnt lgkmcnt(0)" ::: "memory");
    if (t + 1 < nt) {
      if (t + 2 < nt) {
        asm volatile("s_waitcnt vmcnt(8)" ::: "memory");
      } else {
        asm volatile("s_waitcnt vmcnt(4)" ::: "memory");
      }
    }
    BAR();
    // ---------- phase B: read kc0(t+1)->C, stage kc1(t+2), MFMA on N ----------
    if (t + 1 < nt) {
#pragma unroll
      for (int i = 0; i < 8; i++) aC[i] = *(const bf16x8*)(lds0 + nb + rdA + i * 512);
#pragma unroll
      for (int i = 0; i < 4; i++) bC[i] = *(const bf16x8*)(lds0 + nb + 16384 + rdB + i * 512);
    }
    if (t + 2 < nt) {
      GLD(gA0 + KMAP(ko2 + 32), base + 8192 + e0);
      GLD(gA1 + KMAP(ko2 + 32), base + 8192 + e1);
      GLD(gB0 + ko2 + 32, base + 24576 + e0);
      GLD(gB1 + ko2 + 32, base + 24576 + e1);
    }
    __builtin_amdgcn_s_setprio(1);
#pragma unroll
    for (int mi = 0; mi < 8; mi++)
#pragma unroll
      for (int ni = 0; ni < 4; ni++)
        acc[mi][ni] = __builtin_amdgcn_mfma_f32_16x16x32_bf16(aN[mi], bN[ni], acc[mi][ni], 0, 0, 0);
    __builtin_amdgcn_s_setprio(0);
    asm volatile("s_waitcnt lgkmcnt(0)" ::: "memory");
    if (t + 1 < nt) {
      if (t + 2 < nt) {
        asm volatile("s_waitcnt vmcnt(8)" ::: "memory");
      } else {
        asm volatile("s_waitcnt vmcnt(0)" ::: "memory");
      }
    }
    BAR();
  }
#undef GLD
#undef KMAP

  // -------- epilogue: TILE-MAJOR C write (contiguous 128KB per block) --------
  u16* outT = outb + ((((long)z * gy + byi) * gx + bxi) << 16);
  const float* biasz = (MODE == 2) ? (bias + (long)z * N) : bias;
#pragma unroll
  for (int ni = 0; ni < 4; ni++) {
    int cl = wc * 64 + ni * 16 + l15;
    float bcol = (MODE == 2) ? biasz[bn + cl] : 0.0f;
#pragma unroll
    for (int mi = 0; mi < 8; mi++) {
#pragma unroll
      for (int r = 0; r < 4; r++) {
        int rl = wr * 128 + mi * 16 + l4 * 4 + r;
        float v = acc[mi][ni][r];
        if (MODE == 2) {
          float u = v + bcol;
          float zz = 0.7978845608f * (u + 0.044715f * u * u * u);
          float tt = __expf(2.0f * zz);
          float gel = u * (1.0f - 1.0f / (tt + 1.0f));
          v = gel * score[(bm + rl) * 4 + z];
        }
        outT[rl * 256 + cl] = f2bf(v);
      }
    }
  }
}

// ------- flash attention (causal), writes plain a[N,1024] -------------
__global__ __launch_bounds__(256) void attn_kernel(const u16* __restrict__ qkv,
                                                   u16* __restrict__ aout) {
  __shared__ __align__(16) u16 Kt[32 * 64];
  __shared__ __align__(16) u16 VT[64 * 32];
  __shared__ __align__(16) u16 Pl[4][16 * 32];
  int tid = threadIdx.x, wave = tid >> 6, lane = tid & 63;
  int l15 = lane & 15, l4 = lane >> 4;
  int qblk = blockIdx.x, bh = blockIdx.y;
  int b = bh >> 4, h = bh & 15;
  int q0 = qblk * 64 + wave * 16;
  const long LD = 3072;

  bf16x8 qf[2];
  {
    const u16* qp = qkv + (long)(b * 1024 + q0 + l15) * LD + h * 64 + l4 * 8;
    qf[0] = *(const bf16x8*)qp;
    qf[1] = *(const bf16x8*)(qp + 32);
  }
  f32x4 acc[4] = {};
  float m_run = -1e30f, l_run = 0.0f;
  int kv_end = qblk * 64 + 64;

  for (int kv0 = 0; kv0 < kv_end; kv0 += 32) {
    {
      int r = tid >> 3, c = (tid & 7) * 8;
      const u16* kp = qkv + (long)(b * 1024 + kv0 + r) * LD + 1024 + h * 64 + c;
      *(u16x8*)&Kt[r * 64 + c] = *(const u16x8*)kp;
      u16x8 vv = *(const u16x8*)(kp + 1024);
#pragma unroll
      for (int j = 0; j < 8; j++) VT[(c + j) * 32 + r] = vv[j];
    }
    __syncthreads();
    if (kv0 < q0 + 16) {
      float p[8];
      float pmax = -1e30f;
      int qg = q0 + l15;
#pragma unroll
      for (int ks = 0; ks < 2; ks++) {
        f32x4 st = {};
#pragma unroll
        for (int kc = 0; kc < 2; kc++) {
          bf16x8 kf = *(const bf16x8*)&Kt[(ks * 16 + l15) * 64 + kc * 32 + l4 * 8];
          st = __builtin_amdgcn_mfma_f32_16x16x32_bf16(kf, qf[kc], st, 0, 0, 0);
        }
#pragma unroll
        for (int r = 0; r < 4; r++) {
          int kvg = kv0 + ks * 16 + l4 * 4 + r;
          float v = st[r] * 0.125f;
          if (kvg > qg) v = -1e30f;
          p[ks * 4 + r] = v;
          pmax = fmaxf(pmax, v);
        }
      }
      pmax = fmaxf(pmax, __shfl_xor(pmax, 16, 64));
      pmax = fmaxf(pmax, __shfl_xor(pmax, 32, 64));
      float m_new = fmaxf(m_run, pmax);
      float alpha = __expf(m_run - m_new);
      float rsum = 0.f;
#pragma unroll
      for (int i = 0; i < 8; i++) {
        p[i] = __expf(p[i] - m_new);
        rsum += p[i];
      }
      rsum += __shfl_xor(rsum, 16, 64);
      rsum += __shfl_xor(rsum, 32, 64);
      l_run = l_run * alpha + rsum;
      m_run = m_new;
      float af4[4];
#pragma unroll
      for (int r = 0; r < 4; r++) af4[r] = __shfl(alpha, l4 * 4 + r, 64);
#pragma unroll
      for (int i = 0; i < 4; i++) {
#pragma unroll
        for (int r = 0; r < 4; r++) acc[i][r] *= af4[r];
      }
      u16* pw = &Pl[wave][0];
#pragma unroll
      for (int i = 0; i < 8; i++) {
        int ks = i >> 2, r = i & 3;
        pw[l15 * 32 + ks * 16 + l4 * 4 + r] = f2bf(p[i]);
      }
      bf16x8 pa = *(const bf16x8*)&pw[l15 * 32 + l4 * 8];
#pragma unroll
      for (int i = 0; i < 4; i++) {
        bf16x8 vf = *(const bf16x8*)&VT[(i * 16 + l15) * 32 + l4 * 8];
        acc[i] = __builtin_amdgcn_mfma_f32_16x16x32_bf16(pa, vf, acc[i], 0, 0, 0);
      }
    }
    __syncthreads();
  }

  float linv[4];
#pragma unroll
  for (int r = 0; r < 4; r++) {
    float lv = __shfl(l_run, l4 * 4 + r, 64);
    linv[r] = 1.0f / lv;
  }
#pragma unroll
  for (int r = 0; r < 4; r++) {
    int q = l4 * 4 + r;
    long nrow = (long)b * 1024 + q0 + q;
#pragma unroll
    for (int i = 0; i < 4; i++) {
      int d = h * 64 + i * 16 + l15;
      aout[nrow * 1024 + d] = f2bf(acc[i][r] * linv[r]);
    }
  }
}

// -------- out accumulate (vectorized x4); p2t is TILE-major (4 col-tiles) --------
__global__ __launch_bounds__(256) void accum_out(const float* __restrict__ ybuf,
                                                 const float* __restrict__ score_m,
                                                 const float* __restrict__ bp2,
                                                 const u16* __restrict__ p2t,
                                                 float* __restrict__ out) {
  int n = blockIdx.x, t = threadIdx.x;
  int d0 = t * 4;
  long idx = (long)n * D_ + d0;
  float4 s4 = reinterpret_cast<const float4*>(score_m)[n];
  float4 b0 = *reinterpret_cast<const float4*>(&bp2[d0]);
  float4 b1 = *reinterpret_cast<const float4*>(&bp2[D_ + d0]);
  float4 b2 = *reinterpret_cast<const float4*>(&bp2[2 * D_ + d0]);
  float4 b3 = *reinterpret_cast<const float4*>(&bp2[3 * D_ + d0]);
  float4 v = *reinterpret_cast<const float4*>(&ybuf[idx]);
  v.x += s4.x * b0.x + s4.y * b1.x + s4.z * b2.x + s4.w * b3.x;
  v.y += s4.x * b0.y + s4.y * b1.y + s4.z * b2.y + s4.w * b3.y;
  v.z += s4.x * b0.z + s4.y * b1.z + s4.z * b2.z + s4.w * b3.z;
  v.w += s4.x * b0.w + s4.y * b1.w + s4.z * b2.w + s4.w * b3.w;
#pragma unroll
  for (int zz = 0; zz < 4; zz++) {
    long toff = ((((long)zz * 16 + (n >> 8)) * 4 + (d0 >> 8)) << 16) +
                (long)(n & 255) * 256 + (d0 & 255);
    u16x4 pv = *reinterpret_cast<const u16x4*>(&p2t[toff]);
    v.x += bf2f(pv[0]); v.y += bf2f(pv[1]); v.z += bf2f(pv[2]); v.w += bf2f(pv[3]);
  }
  *reinterpret_cast<float4*>(&out[idx]) = v;
}

extern "C" void kernel_launch(void* const* d_in, const int* in_sizes, int n_in, void* d_out,
                              int out_size, void* d_ws, size_t ws_size, hipStream_t stream) {
  (void)in_sizes; (void)n_in; (void)out_size; (void)ws_size;
  const float* x    = (const float*)d_in[0];
  const float* Wr_a = (const float*)d_in[1];
  const float* br_a = (const float*)d_in[2];
  const float* g_a  = (const float*)d_in[3];
  const float* b_a  = (const float*)d_in[4];
  const float* Wqkv = (const float*)d_in[5];
  const float* bqkv = (const float*)d_in[6];
  const float* Wpr  = (const float*)d_in[7];
  const float* bpr  = (const float*)d_in[8];
  const float* Wr_m = (const float*)d_in[9];
  const float* br_m = (const float*)d_in[10];
  const float* g_m  = (const float*)d_in[11];
  const float* b_m  = (const float*)d_in[12];
  const float* Wfc  = (const float*)d_in[13];
  const float* bfc  = (const float*)d_in[14];
  const float* Wp2  = (const float*)d_in[15];
  const float* bp2  = (const float*)d_in[16];
  float* out = (float*)d_out;

  // ---- workspace: 240.2 MB peak, stream-ordered region reuse ----
  char* ws = (char*)d_ws;
  const size_t MB = 1048576;
  u16* wt_q   = (u16*)(ws + 0);            // [0,24)   attn
  u16* wt_pr  = (u16*)(ws + 0);            // [0,8)    after wt_q dead
  u16* wt_fc  = (u16*)(ws + 0);            // [0,32)   MLP
  u16* A_a    = (u16*)(ws + 32 * MB);      // [32,64)  attn
  u16* wt_p2  = (u16*)(ws + 32 * MB);      // [32,64)  MLP
  u16* qkvb   = (u16*)(ws + 64 * MB);      // [64,88)  attn
  u16* A_fc   = (u16*)(ws + 64 * MB);      // [64,96)  MLP (ln2 output)
  u16* p2t    = (u16*)(ws + 64 * MB);      // [64,96)  after A_fc dead (tile-major)
  u16* qp     = (u16*)(ws + 96 * MB);      // [96,192) attn partials (tile-major)
  u16* prt    = (u16*)(ws + 96 * MB);      // [96,128) after qp dead (tile-major)
  u16* inter  = (u16*)(ws + 96 * MB);      // [96,224) MLP (tile-major, after prt dead)
  u16* abuf   = (u16*)(ws + 192 * MB);     // [192,200) attn out
  float* ybuf = (float*)(ws + 224 * MB);   // [224,240)
  float* score_a = (float*)(ws + 240 * MB);
  float* score_m = (float*)(ws + 240 * MB + 65536);

  dim3 tb(32, 8);
  // ---- attention half ----
  tcvt<<<dim3(3072 / 32, 1024 / 32, 4), tb, 0, stream>>>(Wqkv, wt_q, 1024, 3072);
  ln_router_expand<0, 1><<<N_, 256, 0, stream>>>(x, Wr_a, br_a, g_a, b_a, score_a, A_a,
                                                 (long)4096 * 1024, (long)1024, 1,
                                                 nullptr, nullptr, nullptr, nullptr);
  g8<4, 0><<<dim3(3072 / 256, 4096 / 256, 4), 512, 0, stream>>>(
      A_a, wt_q, 1024, 3072, 1024, nullptr, nullptr, qp,
      (long)4096 * 1024, (long)3072 * 1024);
  mixq<<<(4096 * 384) / 256, 256, 0, stream>>>(qp, score_a, bqkv, qkvb);
  attn_kernel<<<dim3(S_ / 64, B_ * H_), 256, 0, stream>>>(qkvb, abuf);
  tcvt<<<dim3(1024 / 32, 1024 / 32, 4), tb, 0, stream>>>(Wpr, wt_pr, 1024, 1024);
  g8<4, 0><<<dim3(1024 / 256, 4096 / 256, 4), 512, 0, stream>>>(
      abuf, wt_pr, 1024, 1024, 1024, nullptr, nullptr, prt,
      0L, (long)1024 * 1024);

  // ---- MLP half: ln2 (fused y-reconstruction) -> batched fc -> batched p2 -> accum --
  ln_router_expand<1, 1><<<N_, 256, 0, stream>>>(x, Wr_m, br_m, g_m, b_m,
                                                 score_m, A_fc, (long)N_ * 1024, (long)1024,
                                                 0, score_a, bpr, prt, ybuf);
  tcvt<<<dim3(4096 / 32, 1024 / 32, 4), tb, 0, stream>>>(Wfc, wt_fc, 1024, 4096);
  tcvt<<<dim3(1024 / 32, 4096 / 32, 4), tb, 0, stream>>>(Wp2, wt_p2, 4096, 1024);
  // fc: all experts, z = expert (1024 blocks); C tile-major into inter
  g8<2, 0><<<dim3(4096 / 256, 4096 / 256, 4), 512, 0, stream>>>(
      A_fc, wt_fc, 1024, 4096, 1024, score_m, bfc, inter,
      (long)N_ * 1024, (long)4096 * 1024);
  // p2: all experts, z over full K (256 blocks, nt=64); A = tiled inter
  g8<4, 1><<<dim3(1024 / 256, 4096 / 256, 4), 512, 0, stream>>>(
      inter, wt_p2, 4096, 1024, 4096, nullptr, nullptr, p2t,
      (long)N_ * 4096, (long)1024 * 4096);
  accum_out<<<N_, 256, 0, stream>>>(ybuf, score_m, bp2, p2t, out);
}

// Round 18
// 698.871 us; speedup vs baseline: 1.0171x; 1.0171x over previous
//
#include <hip/hip_runtime.h>
#include <hip/hip_bf16.h>

typedef __bf16 bf16x8 __attribute__((ext_vector_type(8)));
typedef float f32x4 __attribute__((ext_vector_type(4)));
typedef unsigned short u16;
typedef u16 u16x8 __attribute__((ext_vector_type(8)));
typedef u16 u16x4 __attribute__((ext_vector_type(4)));

#define B_ 4
#define S_ 1024
#define D_ 1024
#define E_ 4
#define H_ 16
#define FF_ 4096
#define N_ 4096

__device__ __forceinline__ u16 f2bf(float f) {
  __hip_bfloat16 h = __float2bfloat16(f);
  return *reinterpret_cast<u16*>(&h);
}
__device__ __forceinline__ float bf2f(u16 v) {
  return __uint_as_float(((unsigned)v) << 16);
}

#define BAR()                         \
  {                                   \
    asm volatile("" ::: "memory");    \
    __builtin_amdgcn_s_barrier();     \
    asm volatile("" ::: "memory");    \
  }

// ------- transpose + f32->bf16 convert (z-batched): dst[z][c][r] = src[z][r][c] -------
__global__ __launch_bounds__(256) void tcvt(const float* __restrict__ src,
                                            u16* __restrict__ dst, int R, int C) {
  __shared__ float t[32][33];
  long base = (long)blockIdx.z * R * C;
  src += base; dst += base;
  int r0 = blockIdx.y * 32, c0 = blockIdx.x * 32;
  int tx = threadIdx.x, ty = threadIdx.y;  // 32 x 8
#pragma unroll
  for (int i = 0; i < 4; i++)
    t[ty + i * 8][tx] = src[(long)(r0 + ty + i * 8) * C + c0 + tx];
  __syncthreads();
#pragma unroll
  for (int i = 0; i < 4; i++)
    dst[(long)(c0 + ty + i * 8) * R + r0 + tx] = f2bf(t[tx][ty + i * 8]);
}

// ---------------- LN + router softmax (+ optional expert expand), vectorized x4 ------
// YMODE=1: row = X[n] + sum_e s_a[e]*bpr[e] + sum_e s_a[e]*prt[e]; writes ybuf.
// EXPAND=1: Aout[e*stride_e + n*stride_n + d] = (scale? score[e]:1)*(hn*g[e]+b[e]).
template <int YMODE, int EXPAND>
__global__ __launch_bounds__(256) void ln_router_expand(
    const float* __restrict__ X, const float* __restrict__ Wr, const float* __restrict__ br,
    const float* __restrict__ g, const float* __restrict__ bb,
    float* __restrict__ score_out, u16* __restrict__ Aout,
    long stride_e, long stride_n, int scale_flag,
    const float* __restrict__ score_a, const float* __restrict__ bpr,
    const u16* __restrict__ prt, float* __restrict__ ybuf) {
  int n = blockIdx.x, t = threadIdx.x;
  int lane = t & 63, wave = t >> 6;
  int d0 = t * 4;
  const float* xr = X + (long)n * D_;
  float4 xv = *reinterpret_cast<const float4*>(&xr[d0]);
  if (YMODE) {
    float4 sa4 = reinterpret_cast<const float4*>(score_a)[n];
    float sw[4] = {sa4.x, sa4.y, sa4.z, sa4.w};
    float4 b0 = *reinterpret_cast<const float4*>(&bpr[d0]);
    float4 b1 = *reinterpret_cast<const float4*>(&bpr[D_ + d0]);
    float4 b2 = *reinterpret_cast<const float4*>(&bpr[2 * D_ + d0]);
    float4 b3 = *reinterpret_cast<const float4*>(&bpr[3 * D_ + d0]);
    xv.x += sa4.x * b0.x + sa4.y * b1.x + sa4.z * b2.x + sa4.w * b3.x;
    xv.y += sa4.x * b0.y + sa4.y * b1.y + sa4.z * b2.y + sa4.w * b3.y;
    xv.z += sa4.x * b0.z + sa4.y * b1.z + sa4.z * b2.z + sa4.w * b3.z;
    xv.w += sa4.x * b0.w + sa4.y * b1.w + sa4.z * b2.w + sa4.w * b3.w;
    long idx = (long)n * D_ + d0;
#pragma unroll
    for (int zz = 0; zz < 4; zz++) {
      u16x4 pv = *reinterpret_cast<const u16x4*>(&prt[(long)zz * 4194304 + idx]);
      xv.x += sw[zz] * bf2f(pv[0]); xv.y += sw[zz] * bf2f(pv[1]);
      xv.z += sw[zz] * bf2f(pv[2]); xv.w += sw[zz] * bf2f(pv[3]);
    }
    *reinterpret_cast<float4*>(&ybuf[idx]) = xv;
  }
  float vals[6];
  vals[0] = xv.x + xv.y + xv.z + xv.w;
  vals[1] = xv.x * xv.x + xv.y * xv.y + xv.z * xv.z + xv.w * xv.w;
  {
    float4 w0 = reinterpret_cast<const float4*>(Wr)[d0];
    float4 w1 = reinterpret_cast<const float4*>(Wr)[d0 + 1];
    float4 w2 = reinterpret_cast<const float4*>(Wr)[d0 + 2];
    float4 w3 = reinterpret_cast<const float4*>(Wr)[d0 + 3];
    vals[2] = xv.x * w0.x + xv.y * w1.x + xv.z * w2.x + xv.w * w3.x;
    vals[3] = xv.x * w0.y + xv.y * w1.y + xv.z * w2.y + xv.w * w3.y;
    vals[4] = xv.x * w0.z + xv.y * w1.z + xv.z * w2.z + xv.w * w3.z;
    vals[5] = xv.x * w0.w + xv.y * w1.w + xv.z * w2.w + xv.w * w3.w;
  }
#pragma unroll
  for (int o = 1; o < 64; o <<= 1) {
#pragma unroll
    for (int j = 0; j < 6; j++) vals[j] += __shfl_xor(vals[j], o, 64);
  }
  __shared__ float red[4][6];
  if (lane == 0) {
#pragma unroll
    for (int j = 0; j < 6; j++) red[wave][j] = vals[j];
  }
  __syncthreads();
  float tot[6];
#pragma unroll
  for (int j = 0; j < 6; j++) tot[j] = red[0][j] + red[1][j] + red[2][j] + red[3][j];
  float mean = tot[0] * (1.0f / D_);
  float var = tot[1] * (1.0f / D_) - mean * mean;
  float rstd = rsqrtf(var + 1e-5f);
  float lg0 = tot[2] + br[0], lg1 = tot[3] + br[1], lg2 = tot[4] + br[2], lg3 = tot[5] + br[3];
  float mx = fmaxf(fmaxf(lg0, lg1), fmaxf(lg2, lg3));
  float e0 = __expf(lg0 - mx), e1 = __expf(lg1 - mx), e2 = __expf(lg2 - mx), e3 = __expf(lg3 - mx);
  float inv = 1.0f / (e0 + e1 + e2 + e3);
  float sc[4] = {e0 * inv, e1 * inv, e2 * inv, e3 * inv};
  if (t == 0) {
    float4 s4 = make_float4(sc[0], sc[1], sc[2], sc[3]);
    *reinterpret_cast<float4*>(&score_out[(long)n * 4]) = s4;
  }
  float4 hn;
  hn.x = (xv.x - mean) * rstd; hn.y = (xv.y - mean) * rstd;
  hn.z = (xv.z - mean) * rstd; hn.w = (xv.w - mean) * rstd;
  if (EXPAND) {
#pragma unroll
    for (int e = 0; e < 4; e++) {
      float4 ge = *reinterpret_cast<const float4*>(&g[e * D_ + d0]);
      float4 be = *reinterpret_cast<const float4*>(&bb[e * D_ + d0]);
      float s = scale_flag ? sc[e] : 1.0f;
      u16x4 o;
      o[0] = f2bf((hn.x * ge.x + be.x) * s);
      o[1] = f2bf((hn.y * ge.y + be.y) * s);
      o[2] = f2bf((hn.z * ge.z + be.z) * s);
      o[3] = f2bf((hn.w * ge.w + be.w) * s);
      *reinterpret_cast<u16x4*>(&Aout[(long)e * stride_e + (long)n * stride_n + d0]) = o;
    }
  } else {
    u16x4 o;
    o[0] = f2bf(hn.x); o[1] = f2bf(hn.y); o[2] = f2bf(hn.z); o[3] = f2bf(hn.w);
    *reinterpret_cast<u16x4*>(&Aout[(long)n * 1024 + d0]) = o;
  }
}

// ---- mixq: qkvb[n,f] = sum_e qp[e][n,f] + sum_e s[n,e]*bqkv[e,f]  (vector x8) --------
__global__ __launch_bounds__(256) void mixq(const u16* __restrict__ qp,
                                            const float* __restrict__ score_a,
                                            const float* __restrict__ bqkv,
                                            u16* __restrict__ qkvb) {
  int c = blockIdx.x * 256 + threadIdx.x;   // 8-col chunk id; 384 chunks/row
  int n = c / 384, f0 = (c % 384) * 8;
  float4 s4 = reinterpret_cast<const float4*>(score_a)[n];
  float sw[4] = {s4.x, s4.y, s4.z, s4.w};
  float acc[8] = {};
#pragma unroll
  for (int e = 0; e < 4; e++) {
    u16x8 pv = *reinterpret_cast<const u16x8*>(&qp[(long)e * 12582912 + (long)n * 3072 + f0]);
#pragma unroll
    for (int j = 0; j < 8; j++) acc[j] += bf2f(pv[j]) + sw[e] * bqkv[e * 3072 + f0 + j];
  }
  u16x8 o;
#pragma unroll
  for (int j = 0; j < 8; j++) o[j] = f2bf(acc[j]);
  *reinterpret_cast<u16x8*>(&qkvb[(long)n * 3072 + f0]) = o;
}

// ======== 8-wave 256x256 GEMM, reg-double-buffered frags, 2 phases/K-tile ============
// Round-8 K-loop (frozen). Epilogue: row-major scatter with LINE-COHERENT loop order
// (mi,r outer / ni inner): each wave fully writes its contiguous 128B span per row
// before moving on -> stores write-combine, kills the ~2.2x HBM write amplification
// seen with the ni-outer order (chunks of the same line written ~128 stores apart).
// Batched mode (bz!=0): z indexes expert; A += z*az, Bt += z*bz, k0=0; MODE 2 uses
// per-z bias (bias + z*N) and score column z; both modes apply zoff = z*zstride.
template <int MODE>
__global__ __launch_bounds__(512, 2) void g8(
    const u16* __restrict__ A, const u16* __restrict__ Bt, int K, int N, int kslice,
    const float* __restrict__ score, const float* __restrict__ bias,
    u16* __restrict__ outb, int eidx, long zstride, long az, long bz) {
  __shared__ __align__(16) u16 lds0[65536];  // 128 KiB
  const int tid = threadIdx.x;
  const int w = tid >> 6, lane = tid & 63;
  const int l15 = lane & 15, l4 = lane >> 4;
  const int wr = w >> 2, wc = w & 3;

  // ---- XCD-aware bijective swizzle ----
  const int gx = gridDim.x, gy = gridDim.y;
  const int total = gx * gy * gridDim.z;
  const int flat = blockIdx.x + gx * (blockIdx.y + gy * blockIdx.z);
  const int cpx = total >> 3;
  const int nf = (flat & 7) * cpx + (flat >> 3);
  const int bxi = nf % gx;
  const int tmp = nf / gx;
  const int byi = tmp % gy;
  const int z = tmp / gy;

  const long bm = (long)byi * 256, bn = (long)bxi * 256;
  const long k0 = bz ? 0L : (long)z * kslice;
  const u16* Az = bz ? (A + (long)z * az) : A;
  const u16* Btz = bz ? (Bt + (long)z * bz) : Bt;
  const int nt = kslice >> 6;

  // staging geometry
  const int cp = lane & 3;
  const int sr0 = w * 32 + (lane >> 2);
  const int sr1 = sr0 + 16;
  const int cl0 = cp ^ ((sr0 >> 1) & 3);
  const int cl1 = cp ^ ((sr1 >> 1) & 3);
  const u16* gA0 = Az + (bm + sr0) * (long)K + k0 + cl0 * 8;
  const u16* gA1 = Az + (bm + sr1) * (long)K + k0 + cl1 * 8;
  const u16* gB0 = Btz + (bn + sr0) * (long)K + k0 + cl0 * 8;
  const u16* gB1 = Btz + (bn + sr1) * (long)K + k0 + cl1 * 8;
  const int e0 = w * 1024;
  const int e1 = w * 1024 + 512;

  // frag-read bases (u16 units within a region)
  const int chA = l4 ^ ((l15 >> 1) & 3);
  const int rdA = (wr * 128 + l15) * 32 + chA * 8;  // + mi*512
  const int rdB = (wc * 64 + l15) * 32 + chA * 8;   // + ni*512

#define GLD(gsrc, ldsoff)                                                              \
  __builtin_amdgcn_global_load_lds(                                                    \
      (const __attribute__((address_space(1))) void*)(gsrc),                           \
      (__attribute__((address_space(3))) void*)(lds0 + (ldsoff)), 16, 0, 0)

  // -------- prologue: stage tiles 0 and 1 fully --------
  GLD(gA0, 0 + e0);
  GLD(gA1, 0 + e1);
  GLD(gB0, 16384 + e0);
  GLD(gB1, 16384 + e1);
  GLD(gA0 + 32, 8192 + e0);
  GLD(gA1 + 32, 8192 + e1);
  GLD(gB0 + 32, 24576 + e0);
  GLD(gB1 + 32, 24576 + e1);
  if (nt > 1) {
    GLD(gA0 + 64, 32768 + e0);
    GLD(gA1 + 64, 32768 + e1);
    GLD(gB0 + 64, 32768 + 16384 + e0);
    GLD(gB1 + 64, 32768 + 16384 + e1);
    GLD(gA0 + 96, 32768 + 8192 + e0);
    GLD(gA1 + 96, 32768 + 8192 + e1);
    GLD(gB0 + 96, 32768 + 24576 + e0);
    GLD(gB1 + 96, 32768 + 24576 + e1);
    asm volatile("s_waitcnt vmcnt(8)" ::: "memory");
  } else {
    asm volatile("s_waitcnt vmcnt(0)" ::: "memory");
  }
  BAR();

  f32x4 acc[8][4] = {};
  bf16x8 aC[8], bC[4], aN[8], bN[4];

  // initial frag load: kc0 of tile 0
#pragma unroll
  for (int i = 0; i < 8; i++) aC[i] = *(const bf16x8*)(lds0 + rdA + i * 512);
#pragma unroll
  for (int i = 0; i < 4; i++) bC[i] = *(const bf16x8*)(lds0 + 16384 + rdB + i * 512);

  for (int t = 0; t < nt; ++t) {
    const int base = (t & 1) * 32768;
    const int nb = base ^ 32768;
    const long ko2 = (long)(t + 2) * 64;
    // ---------- phase A: read kc1(t)->N, stage kc0(t+2), MFMA on C ----------
#pragma unroll
    for (int i = 0; i < 8; i++) aN[i] = *(const bf16x8*)(lds0 + base + 8192 + rdA + i * 512);
#pragma unroll
    for (int i = 0; i < 4; i++) bN[i] = *(const bf16x8*)(lds0 + base + 24576 + rdB + i * 512);
    if (t + 2 < nt) {
      GLD(gA0 + ko2, base + e0);
      GLD(gA1 + ko2, base + e1);
      GLD(gB0 + ko2, base + 16384 + e0);
      GLD(gB1 + ko2, base + 16384 + e1);
    }
    __builtin_amdgcn_s_setprio(1);
#pragma unroll
    for (int mi = 0; mi < 8; mi++)
#pragma unroll
      for (int ni = 0; ni < 4; ni++)
        acc[mi][ni] = __builtin_amdgcn_mfma_f32_16x16x32_bf16(aC[mi], bC[ni], acc[mi][ni], 0, 0, 0);
    __builtin_amdgcn_s_setprio(0);
    asm volatile("s_waitcnt lgkmcnt(0)" ::: "memory");
    if (t + 1 < nt) {
      if (t + 2 < nt) {
        asm volatile("s_waitcnt vmcnt(8)" ::: "memory");
      } else {
        asm volatile("s_waitcnt vmcnt(4)" ::: "memory");
      }
    }
    BAR();
    // ---------- phase B: read kc0(t+1)->C, stage kc1(t+2), MFMA on N ----------
    if (t + 1 < nt) {
#pragma unroll
      for (int i = 0; i < 8; i++) aC[i] = *(const bf16x8*)(lds0 + nb + rdA + i * 512);
#pragma unroll
      for (int i = 0; i < 4; i++) bC[i] = *(const bf16x8*)(lds0 + nb + 16384 + rdB + i * 512);
    }
    if (t + 2 < nt) {
      GLD(gA0 + ko2 + 32, base + 8192 + e0);
      GLD(gA1 + ko2 + 32, base + 8192 + e1);
      GLD(gB0 + ko2 + 32, base + 24576 + e0);
      GLD(gB1 + ko2 + 32, base + 24576 + e1);
    }
    __builtin_amdgcn_s_setprio(1);
#pragma unroll
    for (int mi = 0; mi < 8; mi++)
#pragma unroll
      for (int ni = 0; ni < 4; ni++)
        acc[mi][ni] = __builtin_amdgcn_mfma_f32_16x16x32_bf16(aN[mi], bN[ni], acc[mi][ni], 0, 0, 0);
    __builtin_amdgcn_s_setprio(0);
    asm volatile("s_waitcnt lgkmcnt(0)" ::: "memory");
    if (t + 1 < nt) {
      if (t + 2 < nt) {
        asm volatile("s_waitcnt vmcnt(8)" ::: "memory");
      } else {
        asm volatile("s_waitcnt vmcnt(0)" ::: "memory");
      }
    }
    BAR();
  }
#undef GLD

  // -------- epilogue: line-coherent scatter (mi,r outer / ni inner) --------
  const long zoff = (long)z * zstride;
  const int ei = bz ? z : eidx;
  const float* biasz = (MODE == 2 && bz) ? (bias + (long)z * N) : bias;
  float b4[4];
  if (MODE == 2) {
#pragma unroll
    for (int ni = 0; ni < 4; ni++) b4[ni] = biasz[bn + wc * 64 + ni * 16 + l15];
  }
#pragma unroll
  for (int mi = 0; mi < 8; mi++) {
#pragma unroll
    for (int r = 0; r < 4; r++) {
      long row = bm + wr * 128 + mi * 16 + l4 * 4 + r;
      float scv = (MODE == 2) ? score[row * 4 + ei] : 0.0f;
      u16* orow = outb + zoff + row * (long)N + bn + wc * 64 + l15;
#pragma unroll
      for (int ni = 0; ni < 4; ni++) {
        float v = acc[mi][ni][r];
        if (MODE == 2) {
          float u = v + b4[ni];
          float zz = 0.7978845608f * (u + 0.044715f * u * u * u);
          float tt = __expf(2.0f * zz);
          v = u * (1.0f - 1.0f / (tt + 1.0f)) * scv;
        }
        orow[ni * 16] = f2bf(v);
      }
    }
  }
}

// ------- flash attention (causal), writes plain a[N,1024] -------------
__global__ __launch_bounds__(256) void attn_kernel(const u16* __restrict__ qkv,
                                                   u16* __restrict__ aout) {
  __shared__ __align__(16) u16 Kt[32 * 64];
  __shared__ __align__(16) u16 VT[64 * 32];
  __shared__ __align__(16) u16 Pl[4][16 * 32];
  int tid = threadIdx.x, wave = tid >> 6, lane = tid & 63;
  int l15 = lane & 15, l4 = lane >> 4;
  int qblk = blockIdx.x, bh = blockIdx.y;
  int b = bh >> 4, h = bh & 15;
  int q0 = qblk * 64 + wave * 16;
  const long LD = 3072;

  bf16x8 qf[2];
  {
    const u16* qp = qkv + (long)(b * 1024 + q0 + l15) * LD + h * 64 + l4 * 8;
    qf[0] = *(const bf16x8*)qp;
    qf[1] = *(const bf16x8*)(qp + 32);
  }
  f32x4 acc[4] = {};
  float m_run = -1e30f, l_run = 0.0f;
  int kv_end = qblk * 64 + 64;

  for (int kv0 = 0; kv0 < kv_end; kv0 += 32) {
    {
      int r = tid >> 3, c = (tid & 7) * 8;
      const u16* kp = qkv + (long)(b * 1024 + kv0 + r) * LD + 1024 + h * 64 + c;
      *(u16x8*)&Kt[r * 64 + c] = *(const u16x8*)kp;
      u16x8 vv = *(const u16x8*)(kp + 1024);
#pragma unroll
      for (int j = 0; j < 8; j++) VT[(c + j) * 32 + r] = vv[j];
    }
    __syncthreads();
    if (kv0 < q0 + 16) {
      float p[8];
      float pmax = -1e30f;
      int qg = q0 + l15;
#pragma unroll
      for (int ks = 0; ks < 2; ks++) {
        f32x4 st = {};
#pragma unroll
        for (int kc = 0; kc < 2; kc++) {
          bf16x8 kf = *(const bf16x8*)&Kt[(ks * 16 + l15) * 64 + kc * 32 + l4 * 8];
          st = __builtin_amdgcn_mfma_f32_16x16x32_bf16(kf, qf[kc], st, 0, 0, 0);
        }
#pragma unroll
        for (int r = 0; r < 4; r++) {
          int kvg = kv0 + ks * 16 + l4 * 4 + r;
          float v = st[r] * 0.125f;
          if (kvg > qg) v = -1e30f;
          p[ks * 4 + r] = v;
          pmax = fmaxf(pmax, v);
        }
      }
      pmax = fmaxf(pmax, __shfl_xor(pmax, 16, 64));
      pmax = fmaxf(pmax, __shfl_xor(pmax, 32, 64));
      float m_new = fmaxf(m_run, pmax);
      float alpha = __expf(m_run - m_new);
      float rsum = 0.f;
#pragma unroll
      for (int i = 0; i < 8; i++) {
        p[i] = __expf(p[i] - m_new);
        rsum += p[i];
      }
      rsum += __shfl_xor(rsum, 16, 64);
      rsum += __shfl_xor(rsum, 32, 64);
      l_run = l_run * alpha + rsum;
      m_run = m_new;
      float af4[4];
#pragma unroll
      for (int r = 0; r < 4; r++) af4[r] = __shfl(alpha, l4 * 4 + r, 64);
#pragma unroll
      for (int i = 0; i < 4; i++) {
#pragma unroll
        for (int r = 0; r < 4; r++) acc[i][r] *= af4[r];
      }
      u16* pw = &Pl[wave][0];
#pragma unroll
      for (int i = 0; i < 8; i++) {
        int ks = i >> 2, r = i & 3;
        pw[l15 * 32 + ks * 16 + l4 * 4 + r] = f2bf(p[i]);
      }
      bf16x8 pa = *(const bf16x8*)&pw[l15 * 32 + l4 * 8];
#pragma unroll
      for (int i = 0; i < 4; i++) {
        bf16x8 vf = *(const bf16x8*)&VT[(i * 16 + l15) * 32 + l4 * 8];
        acc[i] = __builtin_amdgcn_mfma_f32_16x16x32_bf16(pa, vf, acc[i], 0, 0, 0);
      }
    }
    __syncthreads();
  }

  float linv[4];
#pragma unroll
  for (int r = 0; r < 4; r++) {
    float lv = __shfl(l_run, l4 * 4 + r, 64);
    linv[r] = 1.0f / lv;
  }
#pragma unroll
  for (int r = 0; r < 4; r++) {
    int q = l4 * 4 + r;
    long nrow = (long)b * 1024 + q0 + q;
#pragma unroll
    for (int i = 0; i < 4; i++) {
      int d = h * 64 + i * 16 + l15;
      aout[nrow * 1024 + d] = f2bf(acc[i][r] * linv[r]);
    }
  }
}

// -------- out accumulate (vectorized x4) --------
__global__ __launch_bounds__(256) void accum_out(const float* __restrict__ ybuf,
                                                 const float* __restrict__ score_m,
                                                 const float* __restrict__ bp2,
                                                 const u16* __restrict__ p2t,
                                                 float* __restrict__ out) {
  int n = blockIdx.x, t = threadIdx.x;
  int d0 = t * 4;
  long idx = (long)n * D_ + d0;
  float4 s4 = reinterpret_cast<const float4*>(score_m)[n];
  float4 b0 = *reinterpret_cast<const float4*>(&bp2[d0]);
  float4 b1 = *reinterpret_cast<const float4*>(&bp2[D_ + d0]);
  float4 b2 = *reinterpret_cast<const float4*>(&bp2[2 * D_ + d0]);
  float4 b3 = *reinterpret_cast<const float4*>(&bp2[3 * D_ + d0]);
  float4 v = *reinterpret_cast<const float4*>(&ybuf[idx]);
  v.x += s4.x * b0.x + s4.y * b1.x + s4.z * b2.x + s4.w * b3.x;
  v.y += s4.x * b0.y + s4.y * b1.y + s4.z * b2.y + s4.w * b3.y;
  v.z += s4.x * b0.z + s4.y * b1.z + s4.z * b2.z + s4.w * b3.z;
  v.w += s4.x * b0.w + s4.y * b1.w + s4.z * b2.w + s4.w * b3.w;
#pragma unroll
  for (int zz = 0; zz < 4; zz++) {
    u16x4 pv = *reinterpret_cast<const u16x4*>(&p2t[(long)zz * 4194304 + idx]);
    v.x += bf2f(pv[0]); v.y += bf2f(pv[1]); v.z += bf2f(pv[2]); v.w += bf2f(pv[3]);
  }
  *reinterpret_cast<float4*>(&out[idx]) = v;
}

extern "C" void kernel_launch(void* const* d_in, const int* in_sizes, int n_in, void* d_out,
                              int out_size, void* d_ws, size_t ws_size, hipStream_t stream) {
  (void)in_sizes; (void)n_in; (void)out_size; (void)ws_size;
  const float* x    = (const float*)d_in[0];
  const float* Wr_a = (const float*)d_in[1];
  const float* br_a = (const float*)d_in[2];
  const float* g_a  = (const float*)d_in[3];
  const float* b_a  = (const float*)d_in[4];
  const float* Wqkv = (const float*)d_in[5];
  const float* bqkv = (const float*)d_in[6];
  const float* Wpr  = (const float*)d_in[7];
  const float* bpr  = (const float*)d_in[8];
  const float* Wr_m = (const float*)d_in[9];
  const float* br_m = (const float*)d_in[10];
  const float* g_m  = (const float*)d_in[11];
  const float* b_m  = (const float*)d_in[12];
  const float* Wfc  = (const float*)d_in[13];
  const float* bfc  = (const float*)d_in[14];
  const float* Wp2  = (const float*)d_in[15];
  const float* bp2  = (const float*)d_in[16];
  float* out = (float*)d_out;

  // ---- workspace: 240.2 MB peak, stream-ordered region reuse ----
  char* ws = (char*)d_ws;
  const size_t MB = 1048576;
  u16* wt_q   = (u16*)(ws + 0);            // [0,24)   attn
  u16* wt_pr  = (u16*)(ws + 0);            // [0,8)    after wt_q dead
  u16* wt_fc  = (u16*)(ws + 0);            // [0,32)   MLP
  u16* A_a    = (u16*)(ws + 32 * MB);      // [32,64)  attn
  u16* wt_p2  = (u16*)(ws + 32 * MB);      // [32,64)  MLP
  u16* qkvb   = (u16*)(ws + 64 * MB);      // [64,88)  attn
  u16* A_fc   = (u16*)(ws + 64 * MB);      // [64,96)  MLP (ln2 output)
  u16* p2t    = (u16*)(ws + 64 * MB);      // [64,96)  after A_fc dead
  u16* qp     = (u16*)(ws + 96 * MB);      // [96,192) attn partials
  u16* prt    = (u16*)(ws + 96 * MB);      // [96,128) after qp dead
  u16* inter  = (u16*)(ws + 96 * MB);      // [96,224) MLP (after prt dead)
  u16* abuf   = (u16*)(ws + 192 * MB);     // [192,200) attn out
  float* ybuf = (float*)(ws + 224 * MB);   // [224,240)
  float* score_a = (float*)(ws + 240 * MB);
  float* score_m = (float*)(ws + 240 * MB + 65536);

  dim3 tb(32, 8);
  // ---- attention half ----
  tcvt<<<dim3(3072 / 32, 1024 / 32, 4), tb, 0, stream>>>(Wqkv, wt_q, 1024, 3072);
  ln_router_expand<0, 1><<<N_, 256, 0, stream>>>(x, Wr_a, br_a, g_a, b_a, score_a, A_a,
                                                 (long)4096 * 1024, (long)1024, 1,
                                                 nullptr, nullptr, nullptr, nullptr);
  g8<4><<<dim3(3072 / 256, 4096 / 256, 4), 512, 0, stream>>>(
      A_a, wt_q, 1024, 3072, 1024, nullptr, nullptr, qp, 0,
      (long)4096 * 3072, (long)4096 * 1024, (long)3072 * 1024);
  mixq<<<(4096 * 384) / 256, 256, 0, stream>>>(qp, score_a, bqkv, qkvb);
  attn_kernel<<<dim3(S_ / 64, B_ * H_), 256, 0, stream>>>(qkvb, abuf);
  tcvt<<<dim3(1024 / 32, 1024 / 32, 4), tb, 0, stream>>>(Wpr, wt_pr, 1024, 1024);
  g8<4><<<dim3(1024 / 256, 4096 / 256, 4), 512, 0, stream>>>(
      abuf, wt_pr, 1024, 1024, 1024, nullptr, nullptr, prt, 0,
      (long)4096 * 1024, 0L, (long)1024 * 1024);

  // ---- MLP half: ln2 (fused y-reconstruction) -> batched fc -> batched p2 -> accum --
  ln_router_expand<1, 1><<<N_, 256, 0, stream>>>(x, Wr_m, br_m, g_m, b_m,
                                                 score_m, A_fc, (long)N_ * 1024, (long)1024,
                                                 0, score_a, bpr, prt, ybuf);
  tcvt<<<dim3(4096 / 32, 1024 / 32, 4), tb, 0, stream>>>(Wfc, wt_fc, 1024, 4096);
  tcvt<<<dim3(1024 / 32, 4096 / 32, 4), tb, 0, stream>>>(Wp2, wt_p2, 4096, 1024);
  // fc: all experts, z = expert (1024 blocks)
  g8<2><<<dim3(4096 / 256, 4096 / 256, 4), 512, 0, stream>>>(
      A_fc, wt_fc, 1024, 4096, 1024, score_m, bfc, inter, 0,
      (long)4096 * 4096, (long)N_ * 1024, (long)4096 * 1024);
  // p2: all experts, z = expert over full K (256 blocks, nt=64)
  g8<4><<<dim3(1024 / 256, 4096 / 256, 4), 512, 0, stream>>>(
      inter, wt_p2, 4096, 1024, 4096, nullptr, nullptr, p2t, 0,
      (long)4096 * 1024, (long)N_ * 4096, (long)1024 * 4096);
  accum_out<<<N_, 256, 0, stream>>>(ybuf, score_m, bp2, p2t, out);
}